// Round 1
// baseline (336.850 us; speedup 1.0000x reference)
//
#include <hip/hip_runtime.h>
#include <math.h>

#define NBINS 64
#define HPAD 65
#define BATCH_N 884736   // 96*96*96
#define NTOT   1769472   // 2*BATCH_N

// monotone float->uint key: max over keys == max over floats
__device__ __forceinline__ unsigned fkey(float x){
    unsigned u = __float_as_uint(x);
    return (u & 0x80000000u) ? ~u : (u | 0x80000000u);
}
__device__ __forceinline__ float fdecode(unsigned k){
    return __uint_as_float((k & 0x80000000u) ? (k ^ 0x80000000u) : ~k);
}

// cubic B-spline Parzen window, same branch structure as reference
__device__ __forceinline__ float bspline(float x){
    float ax  = fabsf(x);
    float ax2 = ax*ax;
    float inner = (4.f - 6.f*ax2 + 3.f*ax*ax2) * (1.f/6.f);
    float d = 2.f - ax;
    float outer = d*d*d*(1.f/6.f);
    return ax < 1.f ? inner : (ax < 2.f ? outer : 0.f);
}

// ws layout: unsigned keys[4] = {maxkey(t), maxkey(-t), maxkey(s), maxkey(-s)}
//            float hist[2][4096] at byte offset 16
__global__ void k_minmax(const float4* __restrict__ t4, const float4* __restrict__ s4,
                         int n4, unsigned* __restrict__ keys){
    unsigned mt=0u, mnt=0u, ms=0u, mns=0u;
    int stride = gridDim.x * blockDim.x;
    for (int i = blockIdx.x*blockDim.x + threadIdx.x; i < n4; i += stride){
        float4 a = t4[i];
        float4 b = s4[i];
        mt  = max(mt,  max(max(fkey(a.x),  fkey(a.y)),  max(fkey(a.z),  fkey(a.w))));
        mnt = max(mnt, max(max(fkey(-a.x), fkey(-a.y)), max(fkey(-a.z), fkey(-a.w))));
        ms  = max(ms,  max(max(fkey(b.x),  fkey(b.y)),  max(fkey(b.z),  fkey(b.w))));
        mns = max(mns, max(max(fkey(-b.x), fkey(-b.y)), max(fkey(-b.z), fkey(-b.w))));
    }
    #pragma unroll
    for (int off = 32; off; off >>= 1){
        mt  = max(mt,  __shfl_down(mt,  off));
        mnt = max(mnt, __shfl_down(mnt, off));
        ms  = max(ms,  __shfl_down(ms,  off));
        mns = max(mns, __shfl_down(mns, off));
    }
    if ((threadIdx.x & 63) == 0){
        atomicMax(&keys[0], mt);
        atomicMax(&keys[1], mnt);
        atomicMax(&keys[2], ms);
        atomicMax(&keys[3], mns);
    }
}

// per-block LDS joint histogram (padded stride 65), merged to global via fp32 atomics
__global__ void k_hist(const float* __restrict__ t, const float* __restrict__ s,
                       const unsigned* __restrict__ keys, float* __restrict__ ghist){
    __shared__ float sh[NBINS*HPAD];
    for (int i = threadIdx.x; i < NBINS*HPAD; i += blockDim.x) sh[i] = 0.f;

    float tmax = fdecode(keys[0]), tmin = -fdecode(keys[1]);
    float smax = fdecode(keys[2]), smin = -fdecode(keys[3]);
    float tsc = 64.f / (tmax - tmin);
    float ssc = 64.f / (smax - smin);
    __syncthreads();

    int b = blockIdx.y;
    const float4* t4 = (const float4*)(t + (size_t)b*BATCH_N);
    const float4* s4 = (const float4*)(s + (size_t)b*BATCH_N);
    int base = blockIdx.x * 1024;   // 1024 float4 = 4096 voxels per block
    #pragma unroll
    for (int c = 0; c < 4; ++c){
        int idx = base + c*256 + threadIdx.x;
        float4 tv = t4[idx];
        float4 sv = s4[idx];
        float txs[4] = {tv.x, tv.y, tv.z, tv.w};
        float sxs[4] = {sv.x, sv.y, sv.z, sv.w};
        #pragma unroll
        for (int e = 0; e < 4; ++e){
            float vt = (txs[e] - tmin) * tsc;   // in [0,64]
            float vs = (sxs[e] - smin) * ssc;
            int it0 = (int)floorf(vt) - 1;
            int is0 = (int)floorf(vs) - 1;
            float wt[4], wsv[4];
            #pragma unroll
            for (int k = 0; k < 4; ++k){
                wt[k]  = bspline((float)(it0 + k) - vt);
                wsv[k] = bspline((float)(is0 + k) - vs);
            }
            #pragma unroll
            for (int i2 = 0; i2 < 4; ++i2){
                int it = it0 + i2;
                if ((unsigned)it < 64u){
                    float* row = sh + it*HPAD;
                    float w = wt[i2];
                    #pragma unroll
                    for (int j2 = 0; j2 < 4; ++j2){
                        int is = is0 + j2;
                        if ((unsigned)is < 64u)
                            atomicAdd(&row[is], w * wsv[j2]);
                    }
                }
            }
        }
    }
    __syncthreads();
    float* gh = ghist + b*4096;
    for (int i = threadIdx.x; i < 4096; i += blockDim.x){
        float v = sh[(i >> 6)*HPAD + (i & 63)];
        unsafeAtomicAdd(&gh[i], v);   // native global_atomic_add_f32
    }
}

__device__ __forceinline__ float blockReduceSum(float v, float* red){
    #pragma unroll
    for (int off = 32; off; off >>= 1) v += __shfl_down(v, off);
    int wid = threadIdx.x >> 6, lane = threadIdx.x & 63;
    __syncthreads();              // protect red[] from previous round
    if (lane == 0) red[wid] = v;
    __syncthreads();
    return red[0] + red[1] + red[2] + red[3];
}

__global__ void k_final(const float* __restrict__ hist, float* __restrict__ out){
    __shared__ float sh[2*4096];
    __shared__ float red[4];
    int tid = threadIdx.x;
    for (int i = tid; i < 8192; i += 256) sh[i] = hist[i];
    __syncthreads();

    float loc = 0.f;
    for (int i = tid; i < 8192; i += 256) loc += sh[i];
    float total = blockReduceSum(loc, red);
    float inv = 1.f / total;

    float nmi[2];
    for (int b = 0; b < 2; ++b){
        const float* h = sh + b*4096;
        // joint entropy
        float lj = 0.f;
        for (int i = tid; i < 4096; i += 256){
            float p = h[i]*inv;
            lj += p*logf(p + 1e-12f);
        }
        float Hj = -blockReduceSum(lj, red);
        // target marginal (row sums)
        float lt = 0.f;
        if (tid < 64){
            float r = 0.f;
            for (int j = 0; j < 64; ++j) r += h[tid*64 + j];
            float p = r*inv;
            lt = p*logf(p + 1e-12f);
        }
        float Ht = -blockReduceSum(lt, red);
        // source marginal (col sums)
        float ls = 0.f;
        if (tid < 64){
            float c = 0.f;
            for (int j = 0; j < 64; ++j) c += h[j*64 + tid];
            float p = c*inv;
            ls = p*logf(p + 1e-12f);
        }
        float Hs = -blockReduceSum(ls, red);
        nmi[b] = (Ht + Hs) / Hj;
    }
    if (tid == 0) out[0] = -0.5f*(nmi[0] + nmi[1]);
}

extern "C" void kernel_launch(void* const* d_in, const int* in_sizes, int n_in,
                              void* d_out, int out_size, void* d_ws, size_t ws_size,
                              hipStream_t stream) {
    const float* t = (const float*)d_in[0];
    const float* s = (const float*)d_in[1];
    float* out = (float*)d_out;
    unsigned* keys = (unsigned*)d_ws;
    float* ghist = (float*)((char*)d_ws + 16);

    // zero min/max keys + global histograms (ws is poisoned each launch)
    hipMemsetAsync(d_ws, 0, 16 + 2*4096*sizeof(float), stream);
    k_minmax<<<512, 256, 0, stream>>>((const float4*)t, (const float4*)s, NTOT/4, keys);
    k_hist<<<dim3(216, 2), 256, 0, stream>>>(t, s, keys, ghist);
    k_final<<<1, 256, 0, stream>>>(ghist, out);
}

// Round 2
// 334.397 us; speedup vs baseline: 1.0073x; 1.0073x over previous
//
#include <hip/hip_runtime.h>
#include <math.h>

#define NBINS 64
#define ROWS 68          // padded rows: bin index -1..66 -> row 0..67
#define COLS 69          // padded cols (odd stride -> good bank spread)
#define BATCH_N 884736   // 96*96*96
#define NTOT   1769472   // 2*BATCH_N
#define N4_BATCH 221184  // BATCH_N/4

// monotone float->uint key: max over keys == max over floats
__device__ __forceinline__ unsigned fkey(float x){
    unsigned u = __float_as_uint(x);
    return (u & 0x80000000u) ? ~u : (u | 0x80000000u);
}
__device__ __forceinline__ float fdecode(unsigned k){
    return __uint_as_float((k & 0x80000000u) ? (k ^ 0x80000000u) : ~k);
}

// cubic B-spline Parzen window, same branch structure as reference
__device__ __forceinline__ float bspline(float x){
    float ax  = fabsf(x);
    float ax2 = ax*ax;
    float inner = (4.f - 6.f*ax2 + 3.f*ax*ax2) * (1.f/6.f);
    float d = 2.f - ax;
    float outer = d*d*d*(1.f/6.f);
    return ax < 1.f ? inner : (ax < 2.f ? outer : 0.f);
}

// fire-and-forget LDS fp32 atomic: relaxed, workgroup scope -> ds_add_f32 (no rtn)
__device__ __forceinline__ void lds_add(float* p, float v){
    __hip_atomic_fetch_add(p, v, __ATOMIC_RELAXED, __HIP_MEMORY_SCOPE_WORKGROUP);
}

// ws layout: unsigned keys[4] = {maxkey(t), maxkey(-t), maxkey(s), maxkey(-s)}
//            float hist[2][4096] at byte offset 16
__global__ void k_minmax(const float4* __restrict__ t4, const float4* __restrict__ s4,
                         int n4, unsigned* __restrict__ keys){
    unsigned mt=0u, mnt=0u, ms=0u, mns=0u;
    int stride = gridDim.x * blockDim.x;
    for (int i = blockIdx.x*blockDim.x + threadIdx.x; i < n4; i += stride){
        float4 a = t4[i];
        float4 b = s4[i];
        mt  = max(mt,  max(max(fkey(a.x),  fkey(a.y)),  max(fkey(a.z),  fkey(a.w))));
        mnt = max(mnt, max(max(fkey(-a.x), fkey(-a.y)), max(fkey(-a.z), fkey(-a.w))));
        ms  = max(ms,  max(max(fkey(b.x),  fkey(b.y)),  max(fkey(b.z),  fkey(b.w))));
        mns = max(mns, max(max(fkey(-b.x), fkey(-b.y)), max(fkey(-b.z), fkey(-b.w))));
    }
    #pragma unroll
    for (int off = 32; off; off >>= 1){
        mt  = max(mt,  __shfl_down(mt,  off));
        mnt = max(mnt, __shfl_down(mnt, off));
        ms  = max(ms,  __shfl_down(ms,  off));
        mns = max(mns, __shfl_down(mns, off));
    }
    if ((threadIdx.x & 63) == 0){
        atomicMax(&keys[0], mt);
        atomicMax(&keys[1], mnt);
        atomicMax(&keys[2], ms);
        atomicMax(&keys[3], mns);
    }
}

// per-block LDS joint histogram, padded 68x69 so all 16 adds are unconditional
__global__ void __launch_bounds__(256, 4)
k_hist(const float* __restrict__ t, const float* __restrict__ s,
       const unsigned* __restrict__ keys, float* __restrict__ ghist){
    __shared__ float sh[ROWS*COLS];
    for (int i = threadIdx.x; i < ROWS*COLS; i += 256) sh[i] = 0.f;

    float tmax = fdecode(keys[0]), tmin = -fdecode(keys[1]);
    float smax = fdecode(keys[2]), smin = -fdecode(keys[3]);
    float tsc = 64.f / (tmax - tmin);
    float ssc = 64.f / (smax - smin);
    __syncthreads();

    int b = blockIdx.y;
    const float4* t4 = (const float4*)(t + (size_t)b*BATCH_N);
    const float4* s4 = (const float4*)(s + (size_t)b*BATCH_N);
    int base = blockIdx.x * 512;   // 512 float4 = 2048 voxels per block
    #pragma unroll
    for (int c = 0; c < 2; ++c){
        int idx = base + c*256 + threadIdx.x;
        float4 tv = t4[idx];
        float4 sv = s4[idx];
        float txs[4] = {tv.x, tv.y, tv.z, tv.w};
        float sxs[4] = {sv.x, sv.y, sv.z, sv.w};
        #pragma unroll
        for (int e = 0; e < 4; ++e){
            float vt = (txs[e] - tmin) * tsc;   // in [0,64]
            float vs = (sxs[e] - smin) * ssc;
            int it0 = (int)floorf(vt);          // 0..64
            int is0 = (int)floorf(vs);
            float ft = (float)it0 - vt;         // in (-1, 0]
            float fs = (float)is0 - vs;
            float wt[4], wsv[4];
            #pragma unroll
            for (int k = 0; k < 4; ++k){
                wt[k]  = bspline(ft + (float)(k - 1));   // arg in (-2,2)
                wsv[k] = bspline(fs + (float)(k - 1));
            }
            // padded base: row = it0-1+1 = it0, col = is0-1+1 = is0
            float* cell = sh + it0*COLS + is0;
            #pragma unroll
            for (int i2 = 0; i2 < 4; ++i2){
                float w = wt[i2];
                #pragma unroll
                for (int j2 = 0; j2 < 4; ++j2){
                    lds_add(&cell[i2*COLS + j2], w * wsv[j2]);
                }
            }
        }
    }
    __syncthreads();
    float* gh = ghist + b*4096;
    for (int i = threadIdx.x; i < 4096; i += 256){
        // interior cell: bin (r,c) lives at padded (r+1, c+1)
        float v = sh[((i >> 6) + 1)*COLS + (i & 63) + 1];
        unsafeAtomicAdd(&gh[i], v);   // native global_atomic_add_f32
    }
}

__device__ __forceinline__ float blockReduceSum(float v, float* red){
    #pragma unroll
    for (int off = 32; off; off >>= 1) v += __shfl_down(v, off);
    int wid = threadIdx.x >> 6, lane = threadIdx.x & 63;
    __syncthreads();              // protect red[] from previous round
    if (lane == 0) red[wid] = v;
    __syncthreads();
    return red[0] + red[1] + red[2] + red[3];
}

__global__ void k_final(const float* __restrict__ hist, float* __restrict__ out){
    __shared__ float sh[2*4096];
    __shared__ float red[4];
    int tid = threadIdx.x;
    for (int i = tid; i < 8192; i += 256) sh[i] = hist[i];
    __syncthreads();

    float loc = 0.f;
    for (int i = tid; i < 8192; i += 256) loc += sh[i];
    float total = blockReduceSum(loc, red);
    float inv = 1.f / total;

    float nmi[2];
    for (int b = 0; b < 2; ++b){
        const float* h = sh + b*4096;
        // joint entropy
        float lj = 0.f;
        for (int i = tid; i < 4096; i += 256){
            float p = h[i]*inv;
            lj += p*logf(p + 1e-12f);
        }
        float Hj = -blockReduceSum(lj, red);
        // target marginal (row sums)
        float lt = 0.f;
        if (tid < 64){
            float r = 0.f;
            for (int j = 0; j < 64; ++j) r += h[tid*64 + j];
            float p = r*inv;
            lt = p*logf(p + 1e-12f);
        }
        float Ht = -blockReduceSum(lt, red);
        // source marginal (col sums)
        float ls = 0.f;
        if (tid < 64){
            float c = 0.f;
            for (int j = 0; j < 64; ++j) c += h[j*64 + tid];
            float p = c*inv;
            ls = p*logf(p + 1e-12f);
        }
        float Hs = -blockReduceSum(ls, red);
        nmi[b] = (Ht + Hs) / Hj;
    }
    if (tid == 0) out[0] = -0.5f*(nmi[0] + nmi[1]);
}

extern "C" void kernel_launch(void* const* d_in, const int* in_sizes, int n_in,
                              void* d_out, int out_size, void* d_ws, size_t ws_size,
                              hipStream_t stream) {
    const float* t = (const float*)d_in[0];
    const float* s = (const float*)d_in[1];
    float* out = (float*)d_out;
    unsigned* keys = (unsigned*)d_ws;
    float* ghist = (float*)((char*)d_ws + 16);

    // zero min/max keys + global histograms (ws is poisoned each launch)
    hipMemsetAsync(d_ws, 0, 16 + 2*4096*sizeof(float), stream);
    k_minmax<<<512, 256, 0, stream>>>((const float4*)t, (const float4*)s, NTOT/4, keys);
    k_hist<<<dim3(432, 2), 256, 0, stream>>>(t, s, keys, ghist);
    k_final<<<1, 256, 0, stream>>>(ghist, out);
}

// Round 3
// 216.154 us; speedup vs baseline: 1.5584x; 1.5470x over previous
//
#include <hip/hip_runtime.h>
#include <math.h>

#define NBINS 64
#define BATCH_N 884736    // 96*96*96
#define NTOT   1769472    // 2*BATCH_N
#define NCHUNK 13824      // BATCH_N / 64
#define ROWS_SH 72        // tile row stride in shorts (144 B: 16B-aligned, 2-way banks)
#define TILE_SH 4608      // 64 rows * 72 shorts
#define WAVE_SH 9216      // A + B tiles per wave (shorts) = 18432 B
#define MROW 66           // merge region row stride (floats)
#define MREG 4224         // 64*66 floats per wave merge region

typedef short v8s __attribute__((ext_vector_type(8)));
typedef float v4f __attribute__((ext_vector_type(4)));

// monotone float->uint key: max over keys == max over floats
__device__ __forceinline__ unsigned fkey(float x){
    unsigned u = __float_as_uint(x);
    return (u & 0x80000000u) ? ~u : (u | 0x80000000u);
}
__device__ __forceinline__ float fdecode(unsigned k){
    return __uint_as_float((k & 0x80000000u) ? (k ^ 0x80000000u) : ~k);
}

// float -> bf16 bits, round-to-nearest-even (inputs are finite, non-NaN)
__device__ __forceinline__ unsigned short f2bf(float x){
    unsigned u = __float_as_uint(x);
    u += 0x7FFFu + ((u >> 16) & 1u);
    return (unsigned short)(u >> 16);
}

// cubic B-spline weights for the 4 bins it0-1..it0+2, u = frac(vt) in [0,1)
__device__ __forceinline__ void bw4(float u, float w[4]){
    float um = 1.f - u;
    float u2 = u*u, um2 = um*um;
    w[0] = um2*um*(1.f/6.f);
    w[3] = u2*u*(1.f/6.f);
    w[1] = 0.6666666666666667f - u2 + 0.5f*u2*u;
    w[2] = 0.6666666666666667f - um2 + 0.5f*um2*um;
}

// ws layout: unsigned keys[4] = {maxkey(t), maxkey(-t), maxkey(s), maxkey(-s)}
//            float hist[2][4096] at byte offset 16
__global__ void k_minmax(const float4* __restrict__ t4, const float4* __restrict__ s4,
                         int n4, unsigned* __restrict__ keys){
    unsigned mt=0u, mnt=0u, ms=0u, mns=0u;
    int stride = gridDim.x * blockDim.x;
    for (int i = blockIdx.x*blockDim.x + threadIdx.x; i < n4; i += stride){
        float4 a = t4[i];
        float4 b = s4[i];
        mt  = max(mt,  max(max(fkey(a.x),  fkey(a.y)),  max(fkey(a.z),  fkey(a.w))));
        mnt = max(mnt, max(max(fkey(-a.x), fkey(-a.y)), max(fkey(-a.z), fkey(-a.w))));
        ms  = max(ms,  max(max(fkey(b.x),  fkey(b.y)),  max(fkey(b.z),  fkey(b.w))));
        mns = max(mns, max(max(fkey(-b.x), fkey(-b.y)), max(fkey(-b.z), fkey(-b.w))));
    }
    #pragma unroll
    for (int off = 32; off; off >>= 1){
        mt  = max(mt,  __shfl_down(mt,  off));
        mnt = max(mnt, __shfl_down(mnt, off));
        ms  = max(ms,  __shfl_down(ms,  off));
        mns = max(mns, __shfl_down(mns, off));
    }
    if ((threadIdx.x & 63) == 0){
        atomicMax(&keys[0], mt);
        atomicMax(&keys[1], mnt);
        atomicMax(&keys[2], ms);
        atomicMax(&keys[3], mns);
    }
}

// joint histogram as tall-skinny GEMM: hist[i][j] = sum_n Wt[i][n]*Ws[j][n]
// wave-private bf16 tiles in LDS (sparse scatter, zero-restore), MFMA accumulate.
__global__ void __launch_bounds__(128, 2)
k_gemm(const float* __restrict__ t, const float* __restrict__ s,
       const unsigned* __restrict__ keys, float* __restrict__ ghist){
    __shared__ int4 smem4[2304];           // 36864 B: 2 waves * (A+B tiles)

    int lane = threadIdx.x & 63;
    int warp = threadIdx.x >> 6;
    int rrow = lane & 15;                  // fragment row/col within 16-tile
    int kgrp = lane >> 4;                  // k-group (quad)

    int4* wz = smem4 + warp*1152;          // this wave's 18432 B region
    short* As = (short*)wz;
    short* Bs = As + TILE_SH;

    // initial clear of this wave's tiles (wave-private: no barrier needed)
    int4 z4 = {0,0,0,0};
    #pragma unroll
    for (int i = 0; i < 18; ++i) wz[i*64 + lane] = z4;

    float tmax = fdecode(keys[0]), tmin = -fdecode(keys[1]);
    float smax = fdecode(keys[2]), smin = -fdecode(keys[3]);
    float tsc = 64.f / (tmax - tmin);
    float ssc = 64.f / (smax - smin);

    int b = blockIdx.y;
    const float* tb = t + (size_t)b*BATCH_N;
    const float* sb = s + (size_t)b*BATCH_N;

    v4f acc[4][4];
    #pragma unroll
    for (int i = 0; i < 4; ++i)
        #pragma unroll
        for (int j = 0; j < 4; ++j)
            acc[i][j] = (v4f){0.f,0.f,0.f,0.f};

    int c0 = blockIdx.x*2 + warp;          // wave index within batch (stride 1024)
    float tcur = tb[(size_t)c0*64 + lane];
    float scur = sb[(size_t)c0*64 + lane];

    for (int c = c0; c < NCHUNK; c += 1024){
        // prefetch next chunk
        int cn = c + 1024; if (cn >= NCHUNK) cn = c;
        float tnext = tb[(size_t)cn*64 + lane];
        float snext = sb[(size_t)cn*64 + lane];

        float vt = (tcur - tmin) * tsc;    // in [0,64]
        float vs = (scur - smin) * ssc;
        int it0 = (int)floorf(vt);
        int is0 = (int)floorf(vs);
        float wt[4], wsv[4];
        bw4(vt - (float)it0, wt);
        bw4(vs - (float)is0, wsv);

        // sparse scatter: lane owns column `lane`; rows it0-1..it0+2 (culled to 0..63)
        #pragma unroll
        for (int k = 0; k < 4; ++k){
            int ra = it0 - 1 + k;
            if ((unsigned)ra < 64u) As[ra*ROWS_SH + lane] = f2bf(wt[k]);
            int rb = is0 - 1 + k;
            if ((unsigned)rb < 64u) Bs[rb*ROWS_SH + lane] = f2bf(wsv[k]);
        }

        // fragments + MFMA (DS ops from one wave complete in order; compiler
        // cannot prove non-aliasing so keeps write->read order)
        #pragma unroll
        for (int kk = 0; kk < 2; ++kk){
            int koff = kk*32 + kgrp*8;
            v8s af[4], bf[4];
            #pragma unroll
            for (int m = 0; m < 4; ++m)
                af[m] = *(const v8s*)(As + (m*16 + rrow)*ROWS_SH + koff);
            #pragma unroll
            for (int n = 0; n < 4; ++n)
                bf[n] = *(const v8s*)(Bs + (n*16 + rrow)*ROWS_SH + koff);
            #pragma unroll
            for (int m = 0; m < 4; ++m)
                #pragma unroll
                for (int n = 0; n < 4; ++n)
                    acc[m][n] = __builtin_amdgcn_mfma_f32_16x16x32_bf16(af[m], bf[n], acc[m][n], 0, 0, 0);
        }

        // zero-restore the scattered entries (keeps tiles clean, no full clear)
        __asm__ volatile("" ::: "memory");
        #pragma unroll
        for (int k = 0; k < 4; ++k){
            int ra = it0 - 1 + k;
            if ((unsigned)ra < 64u) As[ra*ROWS_SH + lane] = 0;
            int rb = is0 - 1 + k;
            if ((unsigned)rb < 64u) Bs[rb*ROWS_SH + lane] = 0;
        }

        tcur = tnext; scur = snext;
    }

    // merge: stage per-wave C into LDS (stride-66 rows: 2-way banks), reduce, atomic out
    __syncthreads();
    float* fsm = (float*)smem4;
    float* myreg = fsm + warp*MREG;
    #pragma unroll
    for (int m = 0; m < 4; ++m)
        #pragma unroll
        for (int n = 0; n < 4; ++n)
            #pragma unroll
            for (int r = 0; r < 4; ++r){
                int rt = m*16 + kgrp*4 + r;
                int cs = n*16 + rrow;
                myreg[rt*MROW + cs] = acc[m][n][r];
            }
    __syncthreads();
    float* gh = ghist + b*4096;
    for (int i = threadIdx.x; i < 4096; i += 128){
        int rt = i >> 6, cs = i & 63;
        float v = fsm[rt*MROW + cs] + fsm[MREG + rt*MROW + cs];
        unsafeAtomicAdd(&gh[i], v);
    }
}

__device__ __forceinline__ float blockReduceSum(float v, float* red){
    #pragma unroll
    for (int off = 32; off; off >>= 1) v += __shfl_down(v, off);
    int wid = threadIdx.x >> 6, lane = threadIdx.x & 63;
    __syncthreads();              // protect red[] from previous round
    if (lane == 0) red[wid] = v;
    __syncthreads();
    return red[0] + red[1] + red[2] + red[3];
}

__global__ void k_final(const float* __restrict__ hist, float* __restrict__ out){
    __shared__ float sh[2*4096];
    __shared__ float red[4];
    int tid = threadIdx.x;
    for (int i = tid; i < 8192; i += 256) sh[i] = hist[i];
    __syncthreads();

    float loc = 0.f;
    for (int i = tid; i < 8192; i += 256) loc += sh[i];
    float total = blockReduceSum(loc, red);
    float inv = 1.f / total;

    float nmi[2];
    for (int b = 0; b < 2; ++b){
        const float* h = sh + b*4096;
        float lj = 0.f;
        for (int i = tid; i < 4096; i += 256){
            float p = h[i]*inv;
            lj += p*logf(p + 1e-12f);
        }
        float Hj = -blockReduceSum(lj, red);
        float lt = 0.f;
        if (tid < 64){
            float r = 0.f;
            for (int j = 0; j < 64; ++j) r += h[tid*64 + j];
            float p = r*inv;
            lt = p*logf(p + 1e-12f);
        }
        float Ht = -blockReduceSum(lt, red);
        float ls = 0.f;
        if (tid < 64){
            float c = 0.f;
            for (int j = 0; j < 64; ++j) c += h[j*64 + tid];
            float p = c*inv;
            ls = p*logf(p + 1e-12f);
        }
        float Hs = -blockReduceSum(ls, red);
        nmi[b] = (Ht + Hs) / Hj;
    }
    if (tid == 0) out[0] = -0.5f*(nmi[0] + nmi[1]);
}

extern "C" void kernel_launch(void* const* d_in, const int* in_sizes, int n_in,
                              void* d_out, int out_size, void* d_ws, size_t ws_size,
                              hipStream_t stream) {
    const float* t = (const float*)d_in[0];
    const float* s = (const float*)d_in[1];
    float* out = (float*)d_out;
    unsigned* keys = (unsigned*)d_ws;
    float* ghist = (float*)((char*)d_ws + 16);

    // zero min/max keys + global histograms (ws is poisoned each launch)
    hipMemsetAsync(d_ws, 0, 16 + 2*4096*sizeof(float), stream);
    k_minmax<<<512, 256, 0, stream>>>((const float4*)t, (const float4*)s, NTOT/4, keys);
    k_gemm<<<dim3(512, 2), 128, 0, stream>>>(t, s, keys, ghist);
    k_final<<<1, 256, 0, stream>>>(ghist, out);
}

// Round 4
// 126.514 us; speedup vs baseline: 2.6626x; 1.7085x over previous
//
#include <hip/hip_runtime.h>
#include <math.h>

#define NBINS 64
#define BATCH_N 884736    // 96*96*96
#define NTOT   1769472    // 2*BATCH_N
#define NCHUNK 13824      // BATCH_N / 64
#define ROWS_SH 72        // tile row stride in shorts (144 B: 16B-aligned, 2-way banks)
#define TILE_SH 4608      // 64 rows * 72 shorts
#define MROW 66           // merge region row stride (floats)
#define MREG 4224         // 64*66 floats per wave merge region

// ws layout: keys at uint offsets {0,16,32,48} (64 B apart: separate cachelines)
//            float hist[2][4096] at byte offset 256
#define KT  0
#define KNT 16
#define KS  32
#define KNS 48

typedef short v8s __attribute__((ext_vector_type(8)));
typedef float v4f __attribute__((ext_vector_type(4)));

// monotone float->uint key: max over keys == max over floats
__device__ __forceinline__ unsigned fkey(float x){
    unsigned u = __float_as_uint(x);
    return (u & 0x80000000u) ? ~u : (u | 0x80000000u);
}
__device__ __forceinline__ float fdecode(unsigned k){
    return __uint_as_float((k & 0x80000000u) ? (k ^ 0x80000000u) : ~k);
}

// float -> bf16 bits, round-to-nearest-even (inputs are finite, non-NaN)
__device__ __forceinline__ unsigned short f2bf(float x){
    unsigned u = __float_as_uint(x);
    u += 0x7FFFu + ((u >> 16) & 1u);
    return (unsigned short)(u >> 16);
}

// cubic B-spline weights for the 4 bins it0-1..it0+2, u = frac(vt) in [0,1)
__device__ __forceinline__ void bw4(float u, float w[4]){
    float um = 1.f - u;
    float u2 = u*u, um2 = um*um;
    w[0] = um2*um*(1.f/6.f);
    w[3] = u2*u*(1.f/6.f);
    w[1] = 0.6666666666666667f - u2 + 0.5f*u2*u;
    w[2] = 0.6666666666666667f - um2 + 0.5f*um2*um;
}

// global min/max via block-reduced atomicMax on monotone keys.
// Also zeroes ghist (16 floats per block) so no 32 KB memset dispatch is needed.
__global__ void __launch_bounds__(256)
k_minmax(const float4* __restrict__ t4, const float4* __restrict__ s4,
         int n4, unsigned* __restrict__ keys, float* __restrict__ gz){
    __shared__ unsigned red[4][4];   // [wave][key]

    if (threadIdx.x < 16) gz[blockIdx.x*16 + threadIdx.x] = 0.f;  // 512 blk * 16 = 8192

    unsigned mt=0u, mnt=0u, ms=0u, mns=0u;
    int stride = gridDim.x * blockDim.x;
    for (int i = blockIdx.x*blockDim.x + threadIdx.x; i < n4; i += stride){
        float4 a = t4[i];
        float4 b = s4[i];
        mt  = max(mt,  max(max(fkey(a.x),  fkey(a.y)),  max(fkey(a.z),  fkey(a.w))));
        mnt = max(mnt, max(max(fkey(-a.x), fkey(-a.y)), max(fkey(-a.z), fkey(-a.w))));
        ms  = max(ms,  max(max(fkey(b.x),  fkey(b.y)),  max(fkey(b.z),  fkey(b.w))));
        mns = max(mns, max(max(fkey(-b.x), fkey(-b.y)), max(fkey(-b.z), fkey(-b.w))));
    }
    #pragma unroll
    for (int off = 32; off; off >>= 1){
        mt  = max(mt,  __shfl_down(mt,  off));
        mnt = max(mnt, __shfl_down(mnt, off));
        ms  = max(ms,  __shfl_down(ms,  off));
        mns = max(mns, __shfl_down(mns, off));
    }
    int wid = threadIdx.x >> 6;
    if ((threadIdx.x & 63) == 0){
        red[wid][0] = mt; red[wid][1] = mnt; red[wid][2] = ms; red[wid][3] = mns;
    }
    __syncthreads();
    if (threadIdx.x == 0){
        unsigned a0 = max(max(red[0][0], red[1][0]), max(red[2][0], red[3][0]));
        unsigned a1 = max(max(red[0][1], red[1][1]), max(red[2][1], red[3][1]));
        unsigned a2 = max(max(red[0][2], red[1][2]), max(red[2][2], red[3][2]));
        unsigned a3 = max(max(red[0][3], red[1][3]), max(red[2][3], red[3][3]));
        atomicMax(&keys[KT],  a0);   // one atomic per block per key; keys 64 B apart
        atomicMax(&keys[KNT], a1);
        atomicMax(&keys[KS],  a2);
        atomicMax(&keys[KNS], a3);
    }
}

// joint histogram as tall-skinny GEMM: hist[i][j] = sum_n Wt[i][n]*Ws[j][n]
// wave-private bf16 tiles in LDS (sparse scatter, zero-restore), MFMA accumulate.
__global__ void __launch_bounds__(128, 2)
k_gemm(const float* __restrict__ t, const float* __restrict__ s,
       const unsigned* __restrict__ keys, float* __restrict__ ghist){
    __shared__ int4 smem4[2304];           // 36864 B: 2 waves * (A+B tiles)

    int lane = threadIdx.x & 63;
    int warp = threadIdx.x >> 6;
    int rrow = lane & 15;                  // fragment row/col within 16-tile
    int kgrp = lane >> 4;                  // k-group (quad)

    int4* wz = smem4 + warp*1152;          // this wave's 18432 B region
    short* As = (short*)wz;
    short* Bs = As + TILE_SH;

    // initial clear of this wave's tiles (wave-private: no barrier needed)
    int4 z4 = {0,0,0,0};
    #pragma unroll
    for (int i = 0; i < 18; ++i) wz[i*64 + lane] = z4;

    float tmax = fdecode(keys[KT]), tmin = -fdecode(keys[KNT]);
    float smax = fdecode(keys[KS]), smin = -fdecode(keys[KNS]);
    float tsc = 64.f / (tmax - tmin);
    float ssc = 64.f / (smax - smin);

    int b = blockIdx.y;
    const float* tb = t + (size_t)b*BATCH_N;
    const float* sb = s + (size_t)b*BATCH_N;

    v4f acc[4][4];
    #pragma unroll
    for (int i = 0; i < 4; ++i)
        #pragma unroll
        for (int j = 0; j < 4; ++j)
            acc[i][j] = (v4f){0.f,0.f,0.f,0.f};

    int c0 = blockIdx.x*2 + warp;          // wave index within batch (stride 1024)
    float tcur = tb[(size_t)c0*64 + lane];
    float scur = sb[(size_t)c0*64 + lane];

    for (int c = c0; c < NCHUNK; c += 1024){
        // prefetch next chunk
        int cn = c + 1024; if (cn >= NCHUNK) cn = c;
        float tnext = tb[(size_t)cn*64 + lane];
        float snext = sb[(size_t)cn*64 + lane];

        float vt = (tcur - tmin) * tsc;    // in [0,64]
        float vs = (scur - smin) * ssc;
        int it0 = (int)floorf(vt);
        int is0 = (int)floorf(vs);
        float wt[4], wsv[4];
        bw4(vt - (float)it0, wt);
        bw4(vs - (float)is0, wsv);

        // sparse scatter: lane owns column `lane`; rows it0-1..it0+2 (culled to 0..63)
        #pragma unroll
        for (int k = 0; k < 4; ++k){
            int ra = it0 - 1 + k;
            if ((unsigned)ra < 64u) As[ra*ROWS_SH + lane] = f2bf(wt[k]);
            int rb = is0 - 1 + k;
            if ((unsigned)rb < 64u) Bs[rb*ROWS_SH + lane] = f2bf(wsv[k]);
        }

        // fragments + MFMA (DS ops from one wave complete in order; compiler
        // cannot prove non-aliasing so keeps write->read order)
        #pragma unroll
        for (int kk = 0; kk < 2; ++kk){
            int koff = kk*32 + kgrp*8;
            v8s af[4], bf[4];
            #pragma unroll
            for (int m = 0; m < 4; ++m)
                af[m] = *(const v8s*)(As + (m*16 + rrow)*ROWS_SH + koff);
            #pragma unroll
            for (int n = 0; n < 4; ++n)
                bf[n] = *(const v8s*)(Bs + (n*16 + rrow)*ROWS_SH + koff);
            #pragma unroll
            for (int m = 0; m < 4; ++m)
                #pragma unroll
                for (int n = 0; n < 4; ++n)
                    acc[m][n] = __builtin_amdgcn_mfma_f32_16x16x32_bf16(af[m], bf[n], acc[m][n], 0, 0, 0);
        }

        // zero-restore the scattered entries (keeps tiles clean, no full clear)
        __asm__ volatile("" ::: "memory");
        #pragma unroll
        for (int k = 0; k < 4; ++k){
            int ra = it0 - 1 + k;
            if ((unsigned)ra < 64u) As[ra*ROWS_SH + lane] = 0;
            int rb = is0 - 1 + k;
            if ((unsigned)rb < 64u) Bs[rb*ROWS_SH + lane] = 0;
        }

        tcur = tnext; scur = snext;
    }

    // merge: stage per-wave C into LDS (stride-66 rows: 2-way banks), reduce, atomic out
    __syncthreads();
    float* fsm = (float*)smem4;
    float* myreg = fsm + warp*MREG;
    #pragma unroll
    for (int m = 0; m < 4; ++m)
        #pragma unroll
        for (int n = 0; n < 4; ++n)
            #pragma unroll
            for (int r = 0; r < 4; ++r){
                int rt = m*16 + kgrp*4 + r;
                int cs = n*16 + rrow;
                myreg[rt*MROW + cs] = acc[m][n][r];
            }
    __syncthreads();
    float* gh = ghist + b*4096;
    for (int i = threadIdx.x; i < 4096; i += 128){
        int rt = i >> 6, cs = i & 63;
        float v = fsm[rt*MROW + cs] + fsm[MREG + rt*MROW + cs];
        unsafeAtomicAdd(&gh[i], v);
    }
}

__device__ __forceinline__ float blockReduceSum(float v, float* red){
    #pragma unroll
    for (int off = 32; off; off >>= 1) v += __shfl_down(v, off);
    int wid = threadIdx.x >> 6, lane = threadIdx.x & 63;
    __syncthreads();              // protect red[] from previous round
    if (lane == 0) red[wid] = v;
    __syncthreads();
    return red[0] + red[1] + red[2] + red[3];
}

__global__ void k_final(const float* __restrict__ hist, float* __restrict__ out){
    __shared__ float sh[2*4096];
    __shared__ float red[4];
    int tid = threadIdx.x;
    for (int i = tid; i < 8192; i += 256) sh[i] = hist[i];
    __syncthreads();

    float loc = 0.f;
    for (int i = tid; i < 8192; i += 256) loc += sh[i];
    float total = blockReduceSum(loc, red);
    float inv = 1.f / total;

    float nmi[2];
    for (int b = 0; b < 2; ++b){
        const float* h = sh + b*4096;
        float lj = 0.f;
        for (int i = tid; i < 4096; i += 256){
            float p = h[i]*inv;
            lj += p*logf(p + 1e-12f);
        }
        float Hj = -blockReduceSum(lj, red);
        float lt = 0.f;
        if (tid < 64){
            float r = 0.f;
            for (int j = 0; j < 64; ++j) r += h[tid*64 + j];
            float p = r*inv;
            lt = p*logf(p + 1e-12f);
        }
        float Ht = -blockReduceSum(lt, red);
        float ls = 0.f;
        if (tid < 64){
            float c = 0.f;
            for (int j = 0; j < 64; ++j) c += h[j*64 + tid];
            float p = c*inv;
            ls = p*logf(p + 1e-12f);
        }
        float Hs = -blockReduceSum(ls, red);
        nmi[b] = (Ht + Hs) / Hj;
    }
    if (tid == 0) out[0] = -0.5f*(nmi[0] + nmi[1]);
}

extern "C" void kernel_launch(void* const* d_in, const int* in_sizes, int n_in,
                              void* d_out, int out_size, void* d_ws, size_t ws_size,
                              hipStream_t stream) {
    const float* t = (const float*)d_in[0];
    const float* s = (const float*)d_in[1];
    float* out = (float*)d_out;
    unsigned* keys = (unsigned*)d_ws;                 // 4 keys, 64 B apart
    float* ghist = (float*)((char*)d_ws + 256);

    hipMemsetAsync(d_ws, 0, 256, stream);             // keys only; ghist zeroed in k_minmax
    k_minmax<<<512, 256, 0, stream>>>((const float4*)t, (const float4*)s, NTOT/4, keys, ghist);
    k_gemm<<<dim3(512, 2), 128, 0, stream>>>(t, s, keys, ghist);
    k_final<<<1, 256, 0, stream>>>(ghist, out);
}